// Round 3
// baseline (578.872 us; speedup 1.0000x reference)
//
#include <hip/hip_runtime.h>
#include <hip/hip_fp16.h>

typedef _Float16 half8 __attribute__((ext_vector_type(8)));
typedef float f32x4 __attribute__((ext_vector_type(4)));

__device__ __forceinline__ float tanh_fast(float x) {
  float e = __expf(2.0f * x);
  return 1.0f - 2.0f / (e + 1.0f);
}

__device__ __forceinline__ void gload16(const _Float16* g, _Float16* l) {
  __builtin_amdgcn_global_load_lds((const __attribute__((address_space(1))) void*)g,
                                   (__attribute__((address_space(3))) void*)l,
                                   16, 0, 0);
}

// ---------------- transpose input_v [64][2048][196] f32 -> Vt [64][196][2048] fp16
__global__ __launch_bounds__(256) void k_transpose_v(const float* __restrict__ in,
                                                     _Float16* __restrict__ out) {
  __shared__ float t[64][65];
  int b = blockIdx.z;
  int c0 = blockIdx.y * 64;
  int p0 = blockIdx.x * 64;
  int tid = threadIdx.x;
  int pl = tid & 63;
  #pragma unroll
  for (int s = 0; s < 16; ++s) {
    int cl = (tid >> 6) + s * 4;
    int p = p0 + pl;
    t[cl][pl] = (p < 196) ? in[((size_t)b * 2048 + (c0 + cl)) * 196 + p] : 0.0f;
  }
  __syncthreads();
  int c8 = (tid & 7) * 8;
  #pragma unroll
  for (int s = 0; s < 2; ++s) {
    int p = p0 + (tid >> 3) + s * 32;
    if (p < 196) {
      half8 v;
      #pragma unroll
      for (int j = 0; j < 8; ++j) v[j] = (_Float16)t[c8 + j][(tid >> 3) + s * 32];
      *(half8*)(out + ((size_t)b * 196 + p) * 2048 + c0 + c8) = v;
    }
  }
}

// ---------------- Wv_att [1200][2048] f32 -> fp16, zero-padded to 1280 rows
__global__ __launch_bounds__(256) void k_conv_w(const float* __restrict__ W,
                                                _Float16* __restrict__ Wh) {
  int i = blockIdx.x * 256 + threadIdx.x;  // < 1280*2048
  int n = i >> 11;
  Wh[i] = (n < 1200) ? (_Float16)W[i] : (_Float16)0.0f;
}

// ---------------- wgt init: wgt[b][g][p] = batt[g]
__global__ __launch_bounds__(256) void k_wgt_init(const float* __restrict__ batt,
                                                  float* __restrict__ wgt) {
  int i = blockIdx.x * 256 + threadIdx.x;
  if (i < 25088) wgt[i] = batt[(i / 196) & 1];
}

// ---------------- big MFMA GEMM, barrier-free wave-independent 64x64 tiles,
// explicit fine-grained s_waitcnt vmcnt(8) pipeline (AITER-style), fused
// tanh/xq/tanh + Watt projection epilogue. xatt never materialized.
__global__ __launch_bounds__(128) void k_gemm1(const _Float16* __restrict__ A,
                                               const _Float16* __restrict__ B,
                                               const float* __restrict__ bias,
                                               const float* __restrict__ xq,
                                               const float* __restrict__ Watt,
                                               float* __restrict__ wgt) {
  __shared__ __align__(16) _Float16 sh[2 * 8192];  // 2 waves * 16KB
  int tid = threadIdx.x;
  int wave = tid >> 6;
  int lane = tid & 63;
  int w = blockIdx.x * 2 + wave;   // 0..3723
  int mtile = w / 19;              // 0..195
  int ntile = w % 19;              // 0..18
  int m0 = mtile * 64;
  int n0 = ntile * 64;
  int fr = lane & 15;
  int fq = lane >> 4;

  _Float16* ldsw = sh + wave * 8192;
  _Float16* A0 = ldsw;
  _Float16* B0 = ldsw + 2048;
  _Float16* A1 = ldsw + 4096;
  _Float16* B1 = ldsw + 6144;

  const _Float16* srcA = A + (size_t)(m0 + (lane >> 2)) * 2048 + (lane & 3) * 8;
  const _Float16* srcB = B + (size_t)(n0 + (lane >> 2)) * 2048 + (lane & 3) * 8;

  f32x4 acc[4][4];
  #pragma unroll
  for (int i = 0; i < 4; ++i)
    #pragma unroll
    for (int j = 0; j < 4; ++j) acc[i][j] = (f32x4){0.f, 0.f, 0.f, 0.f};

  auto stage = [&](_Float16* dA, _Float16* dB, int k0) {
    #pragma unroll
    for (int j = 0; j < 4; ++j) {
      gload16(srcA + (size_t)j * 16 * 2048 + k0, dA + j * 512);
      gload16(srcB + (size_t)j * 16 * 2048 + k0, dB + j * 512);
    }
  };
  auto compute = [&](const _Float16* bA, const _Float16* bB) {
    half8 af[4], bf[4];
    #pragma unroll
    for (int mt = 0; mt < 4; ++mt)
      af[mt] = *(const half8*)(bA + (mt * 16 + fr) * 32 + fq * 8);
    #pragma unroll
    for (int nt = 0; nt < 4; ++nt)
      bf[nt] = *(const half8*)(bB + (nt * 16 + fr) * 32 + fq * 8);
    #pragma unroll
    for (int mt = 0; mt < 4; ++mt)
      #pragma unroll
      for (int nt = 0; nt < 4; ++nt)
        acc[mt][nt] = __builtin_amdgcn_mfma_f32_16x16x32_f16(af[mt], bf[nt], acc[mt][nt], 0, 0, 0);
  };

  stage(A0, B0, 0);                       // 8 loads in flight
  for (int kk = 0; kk < 2048; kk += 64) {
    stage(A1, B1, kk + 32);               // 16 in flight
    asm volatile("s_waitcnt vmcnt(8)" ::: "memory");   // A0/B0 landed
    compute(A0, B0);
    if (kk + 64 < 2048) {
      stage(A0, B0, kk + 64);             // 16 in flight
      asm volatile("s_waitcnt vmcnt(8)" ::: "memory"); // A1/B1 landed
    } else {
      asm volatile("s_waitcnt vmcnt(0)" ::: "memory"); // drain tail
    }
    compute(A1, B1);
  }

  // ---- fused epilogue: xa = tanh(tanh(acc+bias)*xq); wgt += xa * Watt
  float s0[16], s1[16];
  #pragma unroll
  for (int i = 0; i < 16; ++i) { s0[i] = 0.f; s1[i] = 0.f; }

  #pragma unroll
  for (int nt = 0; nt < 4; ++nt) {
    int col = n0 + nt * 16 + fr;
    bool ok = col < 1200;
    float bcol = ok ? bias[col] : 0.f;
    float wa0 = ok ? Watt[col] : 0.f;
    float wa1 = ok ? Watt[1200 + col] : 0.f;
    #pragma unroll
    for (int mt = 0; mt < 4; ++mt) {
      #pragma unroll
      for (int r = 0; r < 4; ++r) {
        int row = m0 + mt * 16 + fq * 4 + r;
        int b = row / 196;
        float xqv = ok ? xq[b * 1200 + col] : 0.f;
        float xv = tanh_fast(acc[mt][nt][r] + bcol);
        float xa = tanh_fast(xv * xqv);
        s0[mt * 4 + r] += xa * wa0;
        s1[mt * 4 + r] += xa * wa1;
      }
    }
  }
  #pragma unroll
  for (int i = 0; i < 16; ++i) {
    #pragma unroll
    for (int off = 8; off > 0; off >>= 1) {
      s0[i] += __shfl_down(s0[i], off);
      s1[i] += __shfl_down(s1[i], off);
    }
  }
  if (fr == 0) {
    #pragma unroll
    for (int i = 0; i < 16; ++i) {
      int row = m0 + (i >> 2) * 16 + fq * 4 + (i & 3);
      int b = row / 196;
      int p = row - b * 196;
      atomicAdd(&wgt[(b * 2 + 0) * 196 + p], s0[i]);
      atomicAdd(&wgt[(b * 2 + 1) * 196 + p], s1[i]);
    }
  }
}

// ---------------- softmax over 196 per (b,g); one wave per row
__global__ __launch_bounds__(64) void k_softmax(const float* __restrict__ wgt,
                                                float* __restrict__ att) {
  int bg = blockIdx.x;  // 128
  int lane = threadIdx.x;
  const float* wr = wgt + (size_t)bg * 196;
  float v[4];
  #pragma unroll
  for (int i = 0; i < 4; ++i) {
    int n = lane + i * 64;
    v[i] = (n < 196) ? wr[n] : -1e30f;
  }
  float mx = fmaxf(fmaxf(v[0], v[1]), fmaxf(v[2], v[3]));
  #pragma unroll
  for (int off = 32; off > 0; off >>= 1) mx = fmaxf(mx, __shfl_xor(mx, off));
  float s = 0.f;
  #pragma unroll
  for (int i = 0; i < 4; ++i) {
    int n = lane + i * 64;
    float e = (n < 196) ? __expf(v[i] - mx) : 0.f;
    v[i] = e;
    s += e;
  }
  #pragma unroll
  for (int off = 32; off > 0; off >>= 1) s += __shfl_xor(s, off);
  float inv = 1.f / s;
  #pragma unroll
  for (int i = 0; i < 4; ++i) {
    int n = lane + i * 64;
    if (n < 196) att[(size_t)bg * 196 + n] = v[i] * inv;
  }
}

// ---------------- v_att[b,g,d] = sum_n att[b,g,n] * Vt[b,n,d]
__global__ __launch_bounds__(256) void k_vatt(const _Float16* __restrict__ Vt,
                                              const float* __restrict__ att,
                                              float* __restrict__ v_att) {
  __shared__ float a0s[196], a1s[196];
  int b = blockIdx.y;
  int tid = threadIdx.x;
  if (tid < 196) {
    a0s[tid] = att[((size_t)b * 2 + 0) * 196 + tid];
    a1s[tid] = att[((size_t)b * 2 + 1) * 196 + tid];
  }
  __syncthreads();
  int d = blockIdx.x * 256 + tid;
  const _Float16* vp = Vt + (size_t)b * 196 * 2048 + d;
  float s0 = 0.f, s1 = 0.f;
  for (int n = 0; n < 196; ++n) {
    float v = (float)vp[(size_t)n * 2048];
    s0 += a0s[n] * v;
    s1 += a1s[n] * v;
  }
  v_att[((size_t)b * 2 + 0) * 2048 + d] = s0;
  v_att[((size_t)b * 2 + 1) * 2048 + d] = s1;
}

// ---------------- generic skinny GEMM, M=64, split-K partials
__global__ __launch_bounds__(256) void k_skinny(const float* __restrict__ A1,
                                                const float* __restrict__ A2,
                                                int lda, int strideAz,
                                                const float* __restrict__ W, long strideWz,
                                                int N, int K, int S,
                                                float* __restrict__ P, int ldp, int colOffZ) {
  __shared__ __align__(16) float As[32][64];
  __shared__ __align__(16) float Ws2[32][64];
  int tid = threadIdx.x;
  int z = blockIdx.z;
  int s = blockIdx.y;
  int nt0 = blockIdx.x * 64;
  int tiles = K >> 5;
  int t0 = (s * tiles) / S;
  int t1 = ((s + 1) * tiles) / S;
  int tx = tid & 15, ty = tid >> 4;
  int lm = tid >> 2;
  int lk = (tid & 3) * 8;
  const float* Ab = A1 + (size_t)z * strideAz + (size_t)lm * lda;
  const float* A2b = A2 ? (A2 + (size_t)z * strideAz + (size_t)lm * lda) : nullptr;
  int ng = nt0 + lm;
  const float* Wb = W + (size_t)z * strideWz + (size_t)ng * K;
  bool wok = ng < N;
  float acc[4][4] = {};
  for (int t = t0; t < t1; ++t) {
    int k0 = t * 32;
    __syncthreads();
    #pragma unroll
    for (int j = 0; j < 8; ++j) {
      float v = Ab[k0 + lk + j];
      if (A2b) v *= A2b[k0 + lk + j];
      As[lk + j][lm] = v;
    }
    #pragma unroll
    for (int j = 0; j < 8; ++j) Ws2[lk + j][lm] = wok ? Wb[k0 + lk + j] : 0.0f;
    __syncthreads();
    #pragma unroll
    for (int kk = 0; kk < 32; ++kk) {
      f32x4 a = *(const f32x4*)&As[kk][ty * 4];
      f32x4 wv = *(const f32x4*)&Ws2[kk][tx * 4];
      #pragma unroll
      for (int i = 0; i < 4; ++i)
        #pragma unroll
        for (int j = 0; j < 4; ++j) acc[i][j] += a[i] * wv[j];
    }
  }
  #pragma unroll
  for (int i = 0; i < 4; ++i) {
    int m = ty * 4 + i;
    #pragma unroll
    for (int j = 0; j < 4; ++j) {
      int nl = nt0 + tx * 4 + j;
      if (nl < N) P[((size_t)s * 64 + m) * ldp + z * colOffZ + nl] = acc[i][j];
    }
  }
}

// ---------------- combine partials: out[i] = act(sum_s P[s][i] + bias[i%ldp])
__global__ __launch_bounds__(256) void k_combine(const float* __restrict__ P, int S, int ldp,
                                                 const float* __restrict__ bias,
                                                 float* __restrict__ out, int total, int act) {
  int i = blockIdx.x * 256 + threadIdx.x;
  if (i >= total) return;
  int col = i % ldp;
  float sum = bias[col];
  for (int ss = 0; ss < S; ++ss) sum += P[(size_t)ss * total + i];
  out[i] = act ? tanh_fast(sum) : sum;
}

extern "C" void kernel_launch(void* const* d_in, const int* in_sizes, int n_in,
                              void* d_out, int out_size, void* d_ws, size_t ws_size,
                              hipStream_t stream) {
  const float* input_q = (const float*)d_in[0];
  const float* input_v = (const float*)d_in[1];
  const float* Wv_att  = (const float*)d_in[2];
  const float* bv_att  = (const float*)d_in[3];
  const float* Wq_att  = (const float*)d_in[4];
  const float* bq_att  = (const float*)d_in[5];
  const float* Watt    = (const float*)d_in[6];
  const float* batt    = (const float*)d_in[7];
  const float* Wv_fus  = (const float*)d_in[8];
  const float* bv_fus  = (const float*)d_in[9];
  const float* Wq_fus  = (const float*)d_in[10];
  const float* bq_fus  = (const float*)d_in[11];
  const float* Wc      = (const float*)d_in[12];
  const float* bc      = (const float*)d_in[13];
  float* out = (float*)d_out;

  char* ws = (char*)d_ws;
  _Float16* Vt   = (_Float16*)ws; ws += 51380224;   // 64*196*2048 fp16
  _Float16* Wh   = (_Float16*)ws; ws += 5242880;    // 1280*2048 fp16
  float* xq      = (float*)ws;    ws += 307200;     // 64*1200 f32
  float* att     = (float*)ws;    ws += 100352;     // 64*2*196 f32
  float* v_att   = (float*)ws;    ws += 1048576;    // 64*2*2048 f32
  float* v_fus   = (float*)ws;    ws += 614400;     // 64*2400 f32
  float* q_fus   = (float*)ws;    ws += 614400;     // 64*2400 f32
  float* P       = (float*)ws;    ws += 14745600;   // 3,686,400 f32 partials

  float* x_out   = out;            // [64][3000]
  float* wgt_out = out + 192000;   // [64][2][196]

  const int S = 16;

  // stage conversions + wgt init
  k_transpose_v<<<dim3(4, 32, 64), dim3(256), 0, stream>>>(input_v, Vt);
  k_conv_w<<<dim3(10240), dim3(256), 0, stream>>>(Wv_att, Wh);
  k_wgt_init<<<dim3(98), dim3(256), 0, stream>>>(batt, wgt_out);

  // xq = tanh(input_q @ Wq_att^T + bq_att)
  k_skinny<<<dim3(19, S, 1), dim3(256), 0, stream>>>(input_q, nullptr, 2400, 0,
                                                     Wq_att, 0, 1200, 2400, S, P, 1200, 0);
  k_combine<<<dim3(300), dim3(256), 0, stream>>>(P, S, 1200, bq_att, xq, 76800, 1);

  // q_fus = tanh(input_q @ Wq_fus^T + bq_fus)  (independent of gemm1)
  k_skinny<<<dim3(38, S, 1), dim3(256), 0, stream>>>(input_q, nullptr, 2400, 0,
                                                     Wq_fus, 0, 2400, 2400, S, P + 1228800, 2400, 0);
  k_combine<<<dim3(600), dim3(256), 0, stream>>>(P + 1228800, S, 2400, bq_fus, q_fus, 153600, 1);

  // fused: xv-tanh-xq-tanh-Watt -> wgt (output 1), xatt never materialized
  k_gemm1<<<dim3(1862), dim3(128), 0, stream>>>(Vt, Wh, bv_att, xq, Watt, wgt_out);

  // softmax -> att
  k_softmax<<<dim3(128), dim3(64), 0, stream>>>(wgt_out, att);

  // v_att
  k_vatt<<<dim3(8, 64), dim3(256), 0, stream>>>(Vt, att, v_att);

  // v_fus = tanh(v_att @ Wv_fus^T + bv_fus)
  k_skinny<<<dim3(19, S, 2), dim3(256), 0, stream>>>(v_att, nullptr, 4096, 2048,
                                                     Wv_fus, 1200L * 2048L, 1200, 2048, S, P, 2400, 1200);
  k_combine<<<dim3(600), dim3(256), 0, stream>>>(P, S, 2400, bv_fus, v_fus, 153600, 1);

  // x = (v_fus * q_fus) @ Wc^T + bc  (output 0)
  k_skinny<<<dim3(47, S, 1), dim3(256), 0, stream>>>(v_fus, q_fus, 2400, 0,
                                                     Wc, 0, 3000, 2400, S, P, 3000, 0);
  k_combine<<<dim3(750), dim3(256), 0, stream>>>(P, S, 3000, bc, x_out, 192000, 0);
}

// Round 4
// 514.718 us; speedup vs baseline: 1.1246x; 1.1246x over previous
//
#include <hip/hip_runtime.h>
#include <hip/hip_fp16.h>

typedef _Float16 half8 __attribute__((ext_vector_type(8)));
typedef float f32x4 __attribute__((ext_vector_type(4)));

__device__ __forceinline__ float tanh_fast(float x) {
  float e = __expf(2.0f * x);
  return 1.0f - 2.0f / (e + 1.0f);
}

__device__ __forceinline__ void gload16(const _Float16* g, _Float16* l) {
  __builtin_amdgcn_global_load_lds((const __attribute__((address_space(1))) void*)g,
                                   (__attribute__((address_space(3))) void*)l,
                                   16, 0, 0);
}

// ---------------- transpose input_v [64][2048][196] f32 -> Vt [64][196][2048] fp16
__global__ __launch_bounds__(256) void k_transpose_v(const float* __restrict__ in,
                                                     _Float16* __restrict__ out) {
  __shared__ float t[64][65];
  int b = blockIdx.z;
  int c0 = blockIdx.y * 64;
  int p0 = blockIdx.x * 64;
  int tid = threadIdx.x;
  int pl = tid & 63;
  #pragma unroll
  for (int s = 0; s < 16; ++s) {
    int cl = (tid >> 6) + s * 4;
    int p = p0 + pl;
    t[cl][pl] = (p < 196) ? in[((size_t)b * 2048 + (c0 + cl)) * 196 + p] : 0.0f;
  }
  __syncthreads();
  int c8 = (tid & 7) * 8;
  #pragma unroll
  for (int s = 0; s < 2; ++s) {
    int p = p0 + (tid >> 3) + s * 32;
    if (p < 196) {
      half8 v;
      #pragma unroll
      for (int j = 0; j < 8; ++j) v[j] = (_Float16)t[c8 + j][(tid >> 3) + s * 32];
      *(half8*)(out + ((size_t)b * 196 + p) * 2048 + c0 + c8) = v;
    }
  }
}

// ---------------- prep: Wv_att f32 -> fp16 padded to 1280 rows; wgt init with batt
__global__ __launch_bounds__(256) void k_prep(const float* __restrict__ W,
                                              _Float16* __restrict__ Wh,
                                              const float* __restrict__ batt,
                                              float* __restrict__ wgt) {
  int i = blockIdx.x * 256 + threadIdx.x;  // < 1280*2048
  int n = i >> 11;
  Wh[i] = (n < 1200) ? (_Float16)W[i] : (_Float16)0.0f;
  if (i < 25088) wgt[i] = batt[(i / 196) & 1];
}

// ---------------- big MFMA GEMM: 128x128 block tile, BK=64 (full 128B lines),
// m97-style barriers, XOR-swizzled LDS chunks (conflict-free ds_read_b128),
// fused tanh/xq/tanh + Watt projection epilogue (wgt atomics).
// A: Vt [12544][2048] fp16 ; B: Wh [1280][2048] fp16
__global__ __launch_bounds__(256) void k_gemm1(const _Float16* __restrict__ A,
                                               const _Float16* __restrict__ B,
                                               const float* __restrict__ bias,
                                               const float* __restrict__ xq,
                                               const float* __restrict__ Watt,
                                               float* __restrict__ wgt) {
  // [row][chunk0..7][8 halfs]; LDS chunk c of row r holds global chunk c^(r&7)
  __shared__ __align__(16) _Float16 As[128 * 64];
  __shared__ __align__(16) _Float16 Bs[128 * 64];
  int tid = threadIdx.x;
  int n0 = blockIdx.x * 128;   // 10 tiles (padded N=1280)
  int m0 = blockIdx.y * 128;   // 98 tiles, exact
  int lane = tid & 63;
  int wave = tid >> 6;
  int wm = (wave >> 1) * 64;
  int wn = (wave & 1) * 64;
  int fr = lane & 15;
  int fq = lane >> 4;

  // staging: wave v issue j covers rows v*8+j*32 .. +7; lane l -> row +(l>>3), LDS chunk l&7
  int rsub = lane >> 3;                   // 0..7 ; also row&7
  int gchunk = (lane & 7) ^ rsub;         // global 16B chunk to load
  const _Float16* aSrc = A + (size_t)(m0 + wave * 8 + rsub) * 2048 + gchunk * 8;
  const _Float16* bSrc = B + (size_t)(n0 + wave * 8 + rsub) * 2048 + gchunk * 8;
  _Float16* aDst = As + (wave * 8) * 64;  // wave-uniform base; HW adds lane*16B
  _Float16* bDst = Bs + (wave * 8) * 64;

  f32x4 acc[4][4];
  #pragma unroll
  for (int i = 0; i < 4; ++i)
    #pragma unroll
    for (int j = 0; j < 4; ++j) acc[i][j] = (f32x4){0.f, 0.f, 0.f, 0.f};

  for (int kt = 0; kt < 32; ++kt) {
    int k0 = kt * 64;
    __syncthreads();   // previous compute done before overwriting LDS
    #pragma unroll
    for (int j = 0; j < 4; ++j) {
      gload16(aSrc + k0 + (size_t)j * 32 * 2048, aDst + j * 32 * 64);
      gload16(bSrc + k0 + (size_t)j * 32 * 2048, bDst + j * 32 * 64);
    }
    __syncthreads();   // vmcnt(0) drain + all waves staged
    #pragma unroll
    for (int s = 0; s < 2; ++s) {
      half8 af[4], bf[4];
      #pragma unroll
      for (int mt = 0; mt < 4; ++mt) {
        int row = wm + mt * 16 + fr;
        af[mt] = *(const half8*)(As + row * 64 + (((s * 4 + fq) ^ (fr & 7)) << 3));
      }
      #pragma unroll
      for (int nt = 0; nt < 4; ++nt) {
        int row = wn + nt * 16 + fr;
        bf[nt] = *(const half8*)(Bs + row * 64 + (((s * 4 + fq) ^ (fr & 7)) << 3));
      }
      #pragma unroll
      for (int mt = 0; mt < 4; ++mt)
        #pragma unroll
        for (int nt = 0; nt < 4; ++nt)
          acc[mt][nt] = __builtin_amdgcn_mfma_f32_16x16x32_f16(af[mt], bf[nt], acc[mt][nt], 0, 0, 0);
    }
  }

  // ---- fused epilogue: xa = tanh(tanh(acc+bias)*xq); wgt += xa * Watt
  float s0[16], s1[16];
  #pragma unroll
  for (int i = 0; i < 16; ++i) { s0[i] = 0.f; s1[i] = 0.f; }

  #pragma unroll
  for (int nt = 0; nt < 4; ++nt) {
    int col = n0 + wn + nt * 16 + fr;
    bool ok = col < 1200;
    float bcol = ok ? bias[col] : 0.f;
    float wa0 = ok ? Watt[col] : 0.f;
    float wa1 = ok ? Watt[1200 + col] : 0.f;
    #pragma unroll
    for (int mt = 0; mt < 4; ++mt) {
      #pragma unroll
      for (int r = 0; r < 4; ++r) {
        int row = m0 + wm + mt * 16 + fq * 4 + r;
        int b = row / 196;
        float xqv = ok ? xq[b * 1200 + col] : 0.f;
        float xv = tanh_fast(acc[mt][nt][r] + bcol);
        float xa = tanh_fast(xv * xqv);
        s0[mt * 4 + r] += xa * wa0;
        s1[mt * 4 + r] += xa * wa1;
      }
    }
  }
  #pragma unroll
  for (int i = 0; i < 16; ++i) {
    #pragma unroll
    for (int off = 8; off > 0; off >>= 1) {
      s0[i] += __shfl_down(s0[i], off);
      s1[i] += __shfl_down(s1[i], off);
    }
  }
  if (fr == 0) {
    #pragma unroll
    for (int i = 0; i < 16; ++i) {
      int row = m0 + wm + (i >> 2) * 16 + fq * 4 + (i & 3);
      int b = row / 196;
      int p = row - b * 196;
      atomicAdd(&wgt[(b * 2 + 0) * 196 + p], s0[i]);
      atomicAdd(&wgt[(b * 2 + 1) * 196 + p], s1[i]);
    }
  }
}

// ---------------- softmax over 196 per (b,g); one wave per row
__global__ __launch_bounds__(64) void k_softmax(const float* __restrict__ wgt,
                                                float* __restrict__ att) {
  int bg = blockIdx.x;  // 128
  int lane = threadIdx.x;
  const float* wr = wgt + (size_t)bg * 196;
  float v[4];
  #pragma unroll
  for (int i = 0; i < 4; ++i) {
    int n = lane + i * 64;
    v[i] = (n < 196) ? wr[n] : -1e30f;
  }
  float mx = fmaxf(fmaxf(v[0], v[1]), fmaxf(v[2], v[3]));
  #pragma unroll
  for (int off = 32; off > 0; off >>= 1) mx = fmaxf(mx, __shfl_xor(mx, off));
  float s = 0.f;
  #pragma unroll
  for (int i = 0; i < 4; ++i) {
    int n = lane + i * 64;
    float e = (n < 196) ? __expf(v[i] - mx) : 0.f;
    v[i] = e;
    s += e;
  }
  #pragma unroll
  for (int off = 32; off > 0; off >>= 1) s += __shfl_xor(s, off);
  float inv = 1.f / s;
  #pragma unroll
  for (int i = 0; i < 4; ++i) {
    int n = lane + i * 64;
    if (n < 196) att[(size_t)bg * 196 + n] = v[i] * inv;
  }
}

// ---------------- v_att[b,g,d] = sum_n att[b,g,n] * Vt[b,n,d]
__global__ __launch_bounds__(256) void k_vatt(const _Float16* __restrict__ Vt,
                                              const float* __restrict__ att,
                                              float* __restrict__ v_att) {
  __shared__ float a0s[196], a1s[196];
  int b = blockIdx.y;
  int tid = threadIdx.x;
  if (tid < 196) {
    a0s[tid] = att[((size_t)b * 2 + 0) * 196 + tid];
    a1s[tid] = att[((size_t)b * 2 + 1) * 196 + tid];
  }
  __syncthreads();
  int d = blockIdx.x * 256 + tid;
  const _Float16* vp = Vt + (size_t)b * 196 * 2048 + d;
  float s0 = 0.f, s1 = 0.f;
  for (int n = 0; n < 196; ++n) {
    float v = (float)vp[(size_t)n * 2048];
    s0 += a0s[n] * v;
    s1 += a1s[n] * v;
  }
  v_att[((size_t)b * 2 + 0) * 2048 + d] = s0;
  v_att[((size_t)b * 2 + 1) * 2048 + d] = s1;
}

// ---------------- generic skinny GEMM, M=64, split-K partials
__global__ __launch_bounds__(256) void k_skinny(const float* __restrict__ A1,
                                                const float* __restrict__ A2,
                                                int lda, int strideAz,
                                                const float* __restrict__ W, long strideWz,
                                                int N, int K, int S,
                                                float* __restrict__ P, int ldp, int colOffZ) {
  __shared__ __align__(16) float As[32][64];
  __shared__ __align__(16) float Ws2[32][64];
  int tid = threadIdx.x;
  int z = blockIdx.z;
  int s = blockIdx.y;
  int nt0 = blockIdx.x * 64;
  int tiles = K >> 5;
  int t0 = (s * tiles) / S;
  int t1 = ((s + 1) * tiles) / S;
  int tx = tid & 15, ty = tid >> 4;
  int lm = tid >> 2;
  int lk = (tid & 3) * 8;
  const float* Ab = A1 + (size_t)z * strideAz + (size_t)lm * lda;
  const float* A2b = A2 ? (A2 + (size_t)z * strideAz + (size_t)lm * lda) : nullptr;
  int ng = nt0 + lm;
  const float* Wb = W + (size_t)z * strideWz + (size_t)ng * K;
  bool wok = ng < N;
  float acc[4][4] = {};
  for (int t = t0; t < t1; ++t) {
    int k0 = t * 32;
    __syncthreads();
    #pragma unroll
    for (int j = 0; j < 8; ++j) {
      float v = Ab[k0 + lk + j];
      if (A2b) v *= A2b[k0 + lk + j];
      As[lk + j][lm] = v;
    }
    #pragma unroll
    for (int j = 0; j < 8; ++j) Ws2[lk + j][lm] = wok ? Wb[k0 + lk + j] : 0.0f;
    __syncthreads();
    #pragma unroll
    for (int kk = 0; kk < 32; ++kk) {
      f32x4 a = *(const f32x4*)&As[kk][ty * 4];
      f32x4 wv = *(const f32x4*)&Ws2[kk][tx * 4];
      #pragma unroll
      for (int i = 0; i < 4; ++i)
        #pragma unroll
        for (int j = 0; j < 4; ++j) acc[i][j] += a[i] * wv[j];
    }
  }
  #pragma unroll
  for (int i = 0; i < 4; ++i) {
    int m = ty * 4 + i;
    #pragma unroll
    for (int j = 0; j < 4; ++j) {
      int nl = nt0 + tx * 4 + j;
      if (nl < N) P[((size_t)s * 64 + m) * ldp + z * colOffZ + nl] = acc[i][j];
    }
  }
}

// ---------------- combine partials: out[i] = act(sum_s P[s][i] + bias[i%ldp])
__global__ __launch_bounds__(256) void k_combine(const float* __restrict__ P, int S, int ldp,
                                                 const float* __restrict__ bias,
                                                 float* __restrict__ out, int total, int act) {
  int i = blockIdx.x * 256 + threadIdx.x;
  if (i >= total) return;
  int col = i % ldp;
  float sum = bias[col];
  for (int ss = 0; ss < S; ++ss) sum += P[(size_t)ss * total + i];
  out[i] = act ? tanh_fast(sum) : sum;
}

extern "C" void kernel_launch(void* const* d_in, const int* in_sizes, int n_in,
                              void* d_out, int out_size, void* d_ws, size_t ws_size,
                              hipStream_t stream) {
  const float* input_q = (const float*)d_in[0];
  const float* input_v = (const float*)d_in[1];
  const float* Wv_att  = (const float*)d_in[2];
  const float* bv_att  = (const float*)d_in[3];
  const float* Wq_att  = (const float*)d_in[4];
  const float* bq_att  = (const float*)d_in[5];
  const float* Watt    = (const float*)d_in[6];
  const float* batt    = (const float*)d_in[7];
  const float* Wv_fus  = (const float*)d_in[8];
  const float* bv_fus  = (const float*)d_in[9];
  const float* Wq_fus  = (const float*)d_in[10];
  const float* bq_fus  = (const float*)d_in[11];
  const float* Wc      = (const float*)d_in[12];
  const float* bc      = (const float*)d_in[13];
  float* out = (float*)d_out;

  char* ws = (char*)d_ws;
  _Float16* Vt   = (_Float16*)ws; ws += 51380224;   // 64*196*2048 fp16
  _Float16* Wh   = (_Float16*)ws; ws += 5242880;    // 1280*2048 fp16
  float* xq      = (float*)ws;    ws += 307200;     // 64*1200 f32
  float* att     = (float*)ws;    ws += 100352;     // 64*2*196 f32
  float* v_att   = (float*)ws;    ws += 1048576;    // 64*2*2048 f32
  float* v_fus   = (float*)ws;    ws += 614400;     // 64*2400 f32
  float* q_fus   = (float*)ws;    ws += 614400;     // 64*2400 f32
  float* P       = (float*)ws;    ws += 14745600;   // 3,686,400 f32 partials

  float* x_out   = out;            // [64][3000]
  float* wgt_out = out + 192000;   // [64][2][196]

  const int S = 16;

  // stage conversions + wgt init
  k_transpose_v<<<dim3(4, 32, 64), dim3(256), 0, stream>>>(input_v, Vt);
  k_prep<<<dim3(10240), dim3(256), 0, stream>>>(Wv_att, Wh, batt, wgt_out);

  // xq = tanh(input_q @ Wq_att^T + bq_att)
  k_skinny<<<dim3(19, S, 1), dim3(256), 0, stream>>>(input_q, nullptr, 2400, 0,
                                                     Wq_att, 0, 1200, 2400, S, P, 1200, 0);
  k_combine<<<dim3(300), dim3(256), 0, stream>>>(P, S, 1200, bq_att, xq, 76800, 1);

  // q_fus = tanh(input_q @ Wq_fus^T + bq_fus)
  k_skinny<<<dim3(38, S, 1), dim3(256), 0, stream>>>(input_q, nullptr, 2400, 0,
                                                     Wq_fus, 0, 2400, 2400, S, P + 1228800, 2400, 0);
  k_combine<<<dim3(600), dim3(256), 0, stream>>>(P + 1228800, S, 2400, bq_fus, q_fus, 153600, 1);

  // fused: xv-tanh-xq-tanh-Watt -> wgt (output 1); xatt never materialized
  k_gemm1<<<dim3(10, 98), dim3(256), 0, stream>>>(Vt, Wh, bv_att, xq, Watt, wgt_out);

  // softmax -> att
  k_softmax<<<dim3(128), dim3(64), 0, stream>>>(wgt_out, att);

  // v_att
  k_vatt<<<dim3(8, 64), dim3(256), 0, stream>>>(Vt, att, v_att);

  // v_fus = tanh(v_att @ Wv_fus^T + bv_fus)
  k_skinny<<<dim3(19, S, 2), dim3(256), 0, stream>>>(v_att, nullptr, 4096, 2048,
                                                     Wv_fus, 1200L * 2048L, 1200, 2048, S, P, 2400, 1200);
  k_combine<<<dim3(600), dim3(256), 0, stream>>>(P, S, 2400, bv_fus, v_fus, 153600, 1);

  // x = (v_fus * q_fus) @ Wc^T + bc  (output 0)
  k_skinny<<<dim3(47, S, 1), dim3(256), 0, stream>>>(v_fus, q_fus, 2400, 0,
                                                     Wc, 0, 3000, 2400, S, P, 3000, 0);
  k_combine<<<dim3(750), dim3(256), 0, stream>>>(P, S, 3000, bc, x_out, 192000, 0);
}

// Round 5
// 474.218 us; speedup vs baseline: 1.2207x; 1.0854x over previous
//
#include <hip/hip_runtime.h>
#include <hip/hip_fp16.h>

typedef _Float16 half8 __attribute__((ext_vector_type(8)));
typedef float f32x4 __attribute__((ext_vector_type(4)));

__device__ __forceinline__ float tanh_fast(float x) {
  float e = __expf(2.0f * x);
  return 1.0f - 2.0f / (e + 1.0f);
}

__device__ __forceinline__ void gload16(const _Float16* g, _Float16* l) {
  __builtin_amdgcn_global_load_lds((const __attribute__((address_space(1))) void*)g,
                                   (__attribute__((address_space(3))) void*)l,
                                   16, 0, 0);
}

// ---------------- transpose input_v [64][2048][196] f32 -> Vt [64][196][2048] fp16
__global__ __launch_bounds__(256) void k_transpose_v(const float* __restrict__ in,
                                                     _Float16* __restrict__ out) {
  __shared__ float t[64][65];
  int b = blockIdx.z;
  int c0 = blockIdx.y * 64;
  int p0 = blockIdx.x * 64;
  int tid = threadIdx.x;
  int pl = tid & 63;
  #pragma unroll
  for (int s = 0; s < 16; ++s) {
    int cl = (tid >> 6) + s * 4;
    int p = p0 + pl;
    t[cl][pl] = (p < 196) ? in[((size_t)b * 2048 + (c0 + cl)) * 196 + p] : 0.0f;
  }
  __syncthreads();
  int c8 = (tid & 7) * 8;
  #pragma unroll
  for (int s = 0; s < 2; ++s) {
    int p = p0 + (tid >> 3) + s * 32;
    if (p < 196) {
      half8 v;
      #pragma unroll
      for (int j = 0; j < 8; ++j) v[j] = (_Float16)t[c8 + j][(tid >> 3) + s * 32];
      *(half8*)(out + ((size_t)b * 196 + p) * 2048 + c0 + c8) = v;
    }
  }
}

// ---------------- prep: Wv_att f32 -> fp16 padded to 1280 rows; wgt init with batt
__global__ __launch_bounds__(256) void k_prep(const float* __restrict__ W,
                                              _Float16* __restrict__ Wh,
                                              const float* __restrict__ batt,
                                              float* __restrict__ wgt) {
  int i = blockIdx.x * 256 + threadIdx.x;  // < 1280*2048
  int n = i >> 11;
  Wh[i] = (n < 1200) ? (_Float16)W[i] : (_Float16)0.0f;
  if (i < 25088) wgt[i] = batt[(i / 196) & 1];
}

// ---------------- big MFMA GEMM: 128x128 tile, BK=32 double-buffered LDS,
// AITER-style pipeline: raw s_barrier + s_waitcnt vmcnt(4) — loads stay in
// flight ACROSS barriers; vmcnt(0) only at the tail. Swizzled chunks keep
// ds_read_b128 at free 2-way conflicts. Fused tanh/xq/tanh + Watt epilogue.
__global__ __launch_bounds__(256) void k_gemm1(const _Float16* __restrict__ A,
                                               const _Float16* __restrict__ B,
                                               const float* __restrict__ bias,
                                               const float* __restrict__ xq,
                                               const float* __restrict__ Watt,
                                               float* __restrict__ wgt) {
  // buffer: [128 rows][4 chunks of 8 halfs]; LDS chunk c of row r holds
  // global chunk c ^ ((r>>1)&3)
  __shared__ __align__(16) _Float16 As[2][128 * 32];
  __shared__ __align__(16) _Float16 Bs[2][128 * 32];
  int tid = threadIdx.x;
  int n0 = blockIdx.x * 128;   // 10 tiles (padded N=1280)
  int m0 = blockIdx.y * 128;   // 98 tiles, exact
  int lane = tid & 63;
  int wave = tid >> 6;
  int wm = (wave >> 1) * 64;
  int wn = (wave & 1) * 64;
  int fr = lane & 15;
  int fq = lane >> 4;

  // staging: wave covers rows wave*32 + j*16 + (lane>>2), LDS chunk lane&3
  int rl = lane >> 2;
  int cch = lane & 3;
  int row0 = wave * 32 + rl;
  int row1 = wave * 32 + 16 + rl;
  int g0 = cch ^ ((row0 >> 1) & 3);
  int g1 = cch ^ ((row1 >> 1) & 3);
  const _Float16* aSrc0 = A + (size_t)(m0 + row0) * 2048 + g0 * 8;
  const _Float16* aSrc1 = A + (size_t)(m0 + row1) * 2048 + g1 * 8;
  const _Float16* bSrc0 = B + (size_t)(n0 + row0) * 2048 + g0 * 8;
  const _Float16* bSrc1 = B + (size_t)(n0 + row1) * 2048 + g1 * 8;

  f32x4 acc[4][4];
  #pragma unroll
  for (int i = 0; i < 4; ++i)
    #pragma unroll
    for (int j = 0; j < 4; ++j) acc[i][j] = (f32x4){0.f, 0.f, 0.f, 0.f};

  auto stage = [&](int buf, int k0) {   // 4 loads per wave
    _Float16* dA = &As[buf][(wave * 32) * 32];
    _Float16* dB = &Bs[buf][(wave * 32) * 32];
    gload16(aSrc0 + k0, dA);
    gload16(aSrc1 + k0, dA + 16 * 32);
    gload16(bSrc0 + k0, dB);
    gload16(bSrc1 + k0, dB + 16 * 32);
  };
  int sw = (fr >> 1) & 3;
  auto compute = [&](int buf) {
    half8 af[4], bf[4];
    #pragma unroll
    for (int mt = 0; mt < 4; ++mt)
      af[mt] = *(const half8*)(&As[buf][(wm + mt * 16 + fr) * 32 + ((fq ^ sw) << 3)]);
    #pragma unroll
    for (int nt = 0; nt < 4; ++nt)
      bf[nt] = *(const half8*)(&Bs[buf][(wn + nt * 16 + fr) * 32 + ((fq ^ sw) << 3)]);
    #pragma unroll
    for (int mt = 0; mt < 4; ++mt)
      #pragma unroll
      for (int nt = 0; nt < 4; ++nt)
        acc[mt][nt] = __builtin_amdgcn_mfma_f32_16x16x32_f16(af[mt], bf[nt], acc[mt][nt], 0, 0, 0);
  };

  stage(0, 0);
  stage(1, 32);                          // 8 loads in flight
  for (int kt = 0; kt < 63; ++kt) {
    int cur = kt & 1;
    asm volatile("s_waitcnt vmcnt(4)" ::: "memory");   // cur landed; 4 still flying
    __builtin_amdgcn_s_barrier();
    compute(cur);
    asm volatile("s_waitcnt lgkmcnt(0)" ::: "memory"); // my reads of cur done
    __builtin_amdgcn_s_barrier();                      // all waves done reading cur
    if (kt < 62) stage(cur, (kt + 2) * 32);            // refill cur for kt+2
  }
  asm volatile("s_waitcnt vmcnt(0)" ::: "memory");     // tail drain
  __builtin_amdgcn_s_barrier();
  compute(1);

  // ---- fused epilogue: xa = tanh(tanh(acc+bias)*xq); wgt += xa * Watt
  float s0[16], s1[16];
  #pragma unroll
  for (int i = 0; i < 16; ++i) { s0[i] = 0.f; s1[i] = 0.f; }

  #pragma unroll
  for (int nt = 0; nt < 4; ++nt) {
    int col = n0 + wn + nt * 16 + fr;
    bool ok = col < 1200;
    float bcol = ok ? bias[col] : 0.f;
    float wa0 = ok ? Watt[col] : 0.f;
    float wa1 = ok ? Watt[1200 + col] : 0.f;
    #pragma unroll
    for (int mt = 0; mt < 4; ++mt) {
      #pragma unroll
      for (int r = 0; r < 4; ++r) {
        int row = m0 + wm + mt * 16 + fq * 4 + r;
        int b = row / 196;
        float xqv = ok ? xq[b * 1200 + col] : 0.f;
        float xv = tanh_fast(acc[mt][nt][r] + bcol);
        float xa = tanh_fast(xv * xqv);
        s0[mt * 4 + r] += xa * wa0;
        s1[mt * 4 + r] += xa * wa1;
      }
    }
  }
  #pragma unroll
  for (int i = 0; i < 16; ++i) {
    #pragma unroll
    for (int off = 8; off > 0; off >>= 1) {
      s0[i] += __shfl_down(s0[i], off);
      s1[i] += __shfl_down(s1[i], off);
    }
  }
  if (fr == 0) {
    #pragma unroll
    for (int i = 0; i < 16; ++i) {
      int row = m0 + wm + (i >> 2) * 16 + fq * 4 + (i & 3);
      int b = row / 196;
      int p = row - b * 196;
      atomicAdd(&wgt[(b * 2 + 0) * 196 + p], s0[i]);
      atomicAdd(&wgt[(b * 2 + 1) * 196 + p], s1[i]);
    }
  }
}

// ---------------- v_att[b,g,d] = sum_n softmax(wgt)[b,g,n] * Vt[b,n,d]
// softmax fused: waves 0/1 compute g=0/1 softmax into LDS.
__global__ __launch_bounds__(256) void k_vatt(const _Float16* __restrict__ Vt,
                                              const float* __restrict__ wgt,
                                              float* __restrict__ v_att) {
  __shared__ float a0s[196], a1s[196];
  int b = blockIdx.y;
  int tid = threadIdx.x;
  int wv = tid >> 6, lane = tid & 63;
  if (wv < 2) {
    const float* wr = wgt + ((size_t)b * 2 + wv) * 196;
    float v[4];
    #pragma unroll
    for (int i = 0; i < 4; ++i) {
      int n = lane + i * 64;
      v[i] = (n < 196) ? wr[n] : -1e30f;
    }
    float mx = fmaxf(fmaxf(v[0], v[1]), fmaxf(v[2], v[3]));
    #pragma unroll
    for (int off = 32; off > 0; off >>= 1) mx = fmaxf(mx, __shfl_xor(mx, off));
    float s = 0.f;
    #pragma unroll
    for (int i = 0; i < 4; ++i) {
      int n = lane + i * 64;
      float e = (n < 196) ? __expf(v[i] - mx) : 0.f;
      v[i] = e;
      s += e;
    }
    #pragma unroll
    for (int off = 32; off > 0; off >>= 1) s += __shfl_xor(s, off);
    float inv = 1.f / s;
    float* dst = wv ? a1s : a0s;
    #pragma unroll
    for (int i = 0; i < 4; ++i) {
      int n = lane + i * 64;
      if (n < 196) dst[n] = v[i] * inv;
    }
  }
  __syncthreads();
  int d = blockIdx.x * 256 + tid;
  const _Float16* vp = Vt + (size_t)b * 196 * 2048 + d;
  float s0 = 0.f, s1 = 0.f;
  for (int n = 0; n < 196; ++n) {
    float v = (float)vp[(size_t)n * 2048];
    s0 += a0s[n] * v;
    s1 += a1s[n] * v;
  }
  v_att[((size_t)b * 2 + 0) * 2048 + d] = s0;
  v_att[((size_t)b * 2 + 1) * 2048 + d] = s1;
}

// ---------------- merged Q-branch skinny: xq (N=1200,W=Wq_att) + q_fus (N=2400,W=Wq_fus)
// A = input_q [64][2400]; P layout [s][64][3600]: cols 0..1199 xq, 1200..3599 q_fus
__global__ __launch_bounds__(256) void k_skinnyQ(const float* __restrict__ q,
                                                 const float* __restrict__ Wa,
                                                 const float* __restrict__ Wf,
                                                 int S, float* __restrict__ P) {
  __shared__ __align__(16) float As[32][64];
  __shared__ __align__(16) float Ws2[32][64];
  int tid = threadIdx.x;
  int x = blockIdx.x;              // 0..56
  int s = blockIdx.y;
  bool f = x >= 19;
  const float* W = f ? Wf : Wa;
  int nt0 = f ? (x - 19) * 64 : x * 64;
  int N = f ? 2400 : 1200;
  int colBase = f ? 1200 : 0;
  const int K = 2400;
  int tiles = K >> 5;              // 75
  int t0 = (s * tiles) / S;
  int t1 = ((s + 1) * tiles) / S;
  int tx = tid & 15, ty = tid >> 4;
  int lm = tid >> 2;
  int lk = (tid & 3) * 8;
  const float* Ab = q + (size_t)lm * K;
  int ng = nt0 + lm;
  const float* Wb = W + (size_t)ng * K;
  bool wok = ng < N;
  float acc[4][4] = {};
  for (int t = t0; t < t1; ++t) {
    int k0 = t * 32;
    __syncthreads();
    #pragma unroll
    for (int j = 0; j < 8; ++j) As[lk + j][lm] = Ab[k0 + lk + j];
    #pragma unroll
    for (int j = 0; j < 8; ++j) Ws2[lk + j][lm] = wok ? Wb[k0 + lk + j] : 0.0f;
    __syncthreads();
    #pragma unroll
    for (int kk = 0; kk < 32; ++kk) {
      f32x4 a = *(const f32x4*)&As[kk][ty * 4];
      f32x4 wv = *(const f32x4*)&Ws2[kk][tx * 4];
      #pragma unroll
      for (int i = 0; i < 4; ++i)
        #pragma unroll
        for (int j = 0; j < 4; ++j) acc[i][j] += a[i] * wv[j];
    }
  }
  #pragma unroll
  for (int i = 0; i < 4; ++i) {
    int m = ty * 4 + i;
    #pragma unroll
    for (int j = 0; j < 4; ++j) {
      int nl = nt0 + tx * 4 + j;
      if (nl < N) P[((size_t)s * 64 + m) * 3600 + colBase + nl] = acc[i][j];
    }
  }
}

// ---------------- combineQ: xq and q_fus from merged partials
__global__ __launch_bounds__(256) void k_combineQ(const float* __restrict__ P, int S,
                                                  const float* __restrict__ bq_att,
                                                  const float* __restrict__ bq_fus,
                                                  float* __restrict__ xq,
                                                  float* __restrict__ q_fus) {
  int i = blockIdx.x * 256 + threadIdx.x;  // < 230400
  if (i >= 230400) return;
  int row = i / 3600, col = i % 3600;
  float sum = 0.f;
  for (int ss = 0; ss < S; ++ss) sum += P[(size_t)ss * 230400 + i];
  if (col < 1200) xq[row * 1200 + col] = tanh_fast(sum + bq_att[col]);
  else            q_fus[row * 2400 + col - 1200] = tanh_fast(sum + bq_fus[col - 1200]);
}

// ---------------- generic skinny GEMM, M=64, split-K partials
__global__ __launch_bounds__(256) void k_skinny(const float* __restrict__ A1,
                                                const float* __restrict__ A2,
                                                int lda, int strideAz,
                                                const float* __restrict__ W, long strideWz,
                                                int N, int K, int S,
                                                float* __restrict__ P, int ldp, int colOffZ) {
  __shared__ __align__(16) float As[32][64];
  __shared__ __align__(16) float Ws2[32][64];
  int tid = threadIdx.x;
  int z = blockIdx.z;
  int s = blockIdx.y;
  int nt0 = blockIdx.x * 64;
  int tiles = K >> 5;
  int t0 = (s * tiles) / S;
  int t1 = ((s + 1) * tiles) / S;
  int tx = tid & 15, ty = tid >> 4;
  int lm = tid >> 2;
  int lk = (tid & 3) * 8;
  const float* Ab = A1 + (size_t)z * strideAz + (size_t)lm * lda;
  const float* A2b = A2 ? (A2 + (size_t)z * strideAz + (size_t)lm * lda) : nullptr;
  int ng = nt0 + lm;
  const float* Wb = W + (size_t)z * strideWz + (size_t)ng * K;
  bool wok = ng < N;
  float acc[4][4] = {};
  for (int t = t0; t < t1; ++t) {
    int k0 = t * 32;
    __syncthreads();
    #pragma unroll
    for (int j = 0; j < 8; ++j) {
      float v = Ab[k0 + lk + j];
      if (A2b) v *= A2b[k0 + lk + j];
      As[lk + j][lm] = v;
    }
    #pragma unroll
    for (int j = 0; j < 8; ++j) Ws2[lk + j][lm] = wok ? Wb[k0 + lk + j] : 0.0f;
    __syncthreads();
    #pragma unroll
    for (int kk = 0; kk < 32; ++kk) {
      f32x4 a = *(const f32x4*)&As[kk][ty * 4];
      f32x4 wv = *(const f32x4*)&Ws2[kk][tx * 4];
      #pragma unroll
      for (int i = 0; i < 4; ++i)
        #pragma unroll
        for (int j = 0; j < 4; ++j) acc[i][j] += a[i] * wv[j];
    }
  }
  #pragma unroll
  for (int i = 0; i < 4; ++i) {
    int m = ty * 4 + i;
    #pragma unroll
    for (int j = 0; j < 4; ++j) {
      int nl = nt0 + tx * 4 + j;
      if (nl < N) P[((size_t)s * 64 + m) * ldp + z * colOffZ + nl] = acc[i][j];
    }
  }
}

// ---------------- combineVh: h = tanh(sum + bv_fus) * q_fus  (fused Hadamard)
__global__ __launch_bounds__(256) void k_combineVh(const float* __restrict__ P, int S,
                                                   const float* __restrict__ bv_fus,
                                                   const float* __restrict__ q_fus,
                                                   float* __restrict__ h) {
  int i = blockIdx.x * 256 + threadIdx.x;  // < 153600
  if (i >= 153600) return;
  int col = i % 2400;
  float sum = bv_fus[col];
  for (int ss = 0; ss < S; ++ss) sum += P[(size_t)ss * 153600 + i];
  h[i] = tanh_fast(sum) * q_fus[i];
}

// ---------------- combine: out[i] = sum_s P[s][i] + bias[i%ldp]
__global__ __launch_bounds__(256) void k_combine(const float* __restrict__ P, int S, int ldp,
                                                 const float* __restrict__ bias,
                                                 float* __restrict__ out, int total) {
  int i = blockIdx.x * 256 + threadIdx.x;
  if (i >= total) return;
  float sum = bias[i % ldp];
  for (int ss = 0; ss < S; ++ss) sum += P[(size_t)ss * total + i];
  out[i] = sum;
}

extern "C" void kernel_launch(void* const* d_in, const int* in_sizes, int n_in,
                              void* d_out, int out_size, void* d_ws, size_t ws_size,
                              hipStream_t stream) {
  const float* input_q = (const float*)d_in[0];
  const float* input_v = (const float*)d_in[1];
  const float* Wv_att  = (const float*)d_in[2];
  const float* bv_att  = (const float*)d_in[3];
  const float* Wq_att  = (const float*)d_in[4];
  const float* bq_att  = (const float*)d_in[5];
  const float* Watt    = (const float*)d_in[6];
  const float* batt    = (const float*)d_in[7];
  const float* Wv_fus  = (const float*)d_in[8];
  const float* bv_fus  = (const float*)d_in[9];
  const float* Wq_fus  = (const float*)d_in[10];
  const float* bq_fus  = (const float*)d_in[11];
  const float* Wc      = (const float*)d_in[12];
  const float* bc      = (const float*)d_in[13];
  float* out = (float*)d_out;

  char* ws = (char*)d_ws;
  _Float16* Vt   = (_Float16*)ws; ws += 51380224;   // 64*196*2048 fp16
  _Float16* Wh   = (_Float16*)ws; ws += 5242880;    // 1280*2048 fp16
  float* xq      = (float*)ws;    ws += 307200;     // 64*1200 f32
  float* v_att   = (float*)ws;    ws += 1048576;    // 64*2*2048 f32
  float* v_fus   = (float*)ws;    ws += 614400;     // 64*2400 f32 (becomes h)
  float* q_fus   = (float*)ws;    ws += 614400;     // 64*2400 f32
  float* P       = (float*)ws;    ws += 14745600;   // 3,686,400 f32 partials

  float* x_out   = out;            // [64][3000]
  float* wgt_out = out + 192000;   // [64][2][196]

  const int S = 16;

  // stage conversions + wgt init
  k_transpose_v<<<dim3(4, 32, 64), dim3(256), 0, stream>>>(input_v, Vt);
  k_prep<<<dim3(10240), dim3(256), 0, stream>>>(Wv_att, Wh, batt, wgt_out);

  // merged Q-branch: xq + q_fus
  k_skinnyQ<<<dim3(57, S), dim3(256), 0, stream>>>(input_q, Wq_att, Wq_fus, S, P);
  k_combineQ<<<dim3(900), dim3(256), 0, stream>>>(P, S, bq_att, bq_fus, xq, q_fus);

  // fused: xv-tanh-xq-tanh-Watt -> wgt (output 1); xatt never materialized
  k_gemm1<<<dim3(10, 98), dim3(256), 0, stream>>>(Vt, Wh, bv_att, xq, Watt, wgt_out);

  // softmax (fused) + v_att
  k_vatt<<<dim3(8, 64), dim3(256), 0, stream>>>(Vt, wgt_out, v_att);

  // v_fus partials, then h = tanh(v_fus)*q_fus
  k_skinny<<<dim3(19, S, 2), dim3(256), 0, stream>>>(v_att, nullptr, 4096, 2048,
                                                     Wv_fus, 1200L * 2048L, 1200, 2048, S, P, 2400, 1200);
  k_combineVh<<<dim3(600), dim3(256), 0, stream>>>(P, S, bv_fus, q_fus, v_fus);

  // x = h @ Wc^T + bc  (output 0)
  k_skinny<<<dim3(47, S, 1), dim3(256), 0, stream>>>(v_fus, nullptr, 2400, 0,
                                                     Wc, 0, 3000, 2400, S, P, 3000, 0);
  k_combine<<<dim3(750), dim3(256), 0, stream>>>(P, S, 3000, bc, x_out, 192000);
}